// Round 4
// baseline (142.852 us; speedup 1.0000x reference)
//
#include <hip/hip_runtime.h>

namespace {

typedef float v2f __attribute__((ext_vector_type(2)));

constexpr int NQ = 12;
constexpr int DIM = 1 << NQ;   // 4096
constexpr int THREADS = 256;

// ---------- packed fp32 helpers ----------
__device__ __forceinline__ v2f splat(float s) { return (v2f){ s, s }; }
__device__ __forceinline__ v2f pfma(float s, v2f v, v2f acc) {
    return __builtin_elementwise_fma(splat(s), v, acc);
}
__device__ __forceinline__ v2f pmul(float s, v2f v) { return splat(s) * v; }
__device__ __forceinline__ v2f swn(v2f a) {          // (-a.i, a.r)
    v2f r = __builtin_shufflevector(a, a, 1, 0);
    r.x = -r.x;
    return r;
}
__device__ __forceinline__ v2f cmulp(v2f a, v2f b) { // complex a*b
    return pfma(a.x, b, pmul(a.y, swn(b)));
}

// ---------- wave-uniform gate in SGPRs ----------
struct GateS { float r00, i00, r01, i01, r10, i10, r11, i11; };

__device__ __forceinline__ float rfl(float v) {
    return __int_as_float(__builtin_amdgcn_readfirstlane(__float_as_int(v)));
}
__device__ __forceinline__ GateS loadGateS(const float4* Vs, int g) {
    const float4 a = Vs[g * 2];
    const float4 c = Vs[g * 2 + 1];
    GateS s;
    s.r00 = rfl(a.x); s.i00 = rfl(a.y); s.r01 = rfl(a.z); s.i01 = rfl(a.w);
    s.r10 = rfl(c.x); s.i10 = rfl(c.y); s.r11 = rfl(c.z); s.i11 = rfl(c.w);
    return s;
}

// packed complex butterfly: (x,y) <- (g00 x + g01 y, g10 x + g11 y)
__device__ __forceinline__ void bfp(v2f& x, v2f& y, const GateS& g) {
    const v2f a = x, b = y;
    const v2f as = swn(a), bs = swn(b);
    x = pfma(g.r00, a, pfma(g.i00, as, pfma(g.r01, b, pmul(g.i01, bs))));
    y = pfma(g.r10, a, pfma(g.i10, as, pfma(g.r11, b, pmul(g.i11, bs))));
}

template<int BP>
__device__ __forceinline__ void applyGateP(v2f v[16], const GateS& g) {
    #pragma unroll
    for (int mi = 0; mi < 8; ++mi) {
        const int i0 = ((mi >> BP) << (BP + 1)) | (mi & ((1 << BP) - 1));
        bfp(v[i0], v[i0 | (1 << BP)], g);
    }
}

// ---------- XOR-linear address algebra ----------
// gamma^k: k-fold CNOT-ladder fold, gamma(t) = t ^ (t>>1)
__host__ __device__ constexpr int G(int t, int k) {
    for (int i = 0; i < k; ++i) t = (t ^ (t >> 1)) & 0xFFF;
    return t;
}
// layout shear C (involution), Cm(1)=1 so the gamma-fixed direction stays b128-pairable
__host__ __device__ constexpr int Cm(int t) {
    int lo = 0;
    if (t & 0x010) lo ^= 0x2;
    if (t & 0x020) lo ^= 0x4;
    if (t & 0x040) lo ^= 0x8;
    if (t & 0x080) lo ^= 0x6;
    if (t & 0x100) lo ^= 0xA;
    if (t & 0x200) lo ^= 0xC;
    return t ^ lo;
}
// readout weight mask: w(e) = parity(gamma^{-4}(C(e))), gamma^{-4} = gamma^{12}
__host__ __device__ constexpr int maskE_calc() {
    int m = 0;
    for (int i = 0; i < 12; ++i) {
        int v = G(Cm(1 << i), 12), p = 0;
        while (v) { p ^= (v & 1); v >>= 1; }
        if (p) m |= (1 << i);
    }
    return m;
}
constexpr int MASKE = maskE_calc();

// ---------- one gate layer (layers 1..3) ----------
template<int K>
__device__ __forceinline__ void doLayer(v2f* amp, float4* a4, const float4* Vs, int tid) {
    const int Lo = tid & 15, Hh = tid >> 4;

    // pass 0: qubits 0-3 (t bits 11-8)
    {
        const GateS g0 = loadGateS(Vs, K * NQ + 0);
        const GateS g1 = loadGateS(Vs, K * NQ + 1);
        const GateS g2 = loadGateS(Vs, K * NQ + 2);
        const GateS g3 = loadGateS(Vs, K * NQ + 3);
        const int beta = Cm(G(tid, K));
        v2f v[16];
        #pragma unroll
        for (int j = 0; j < 16; ++j) v[j] = amp[beta ^ Cm(G(j << 8, K))];
        applyGateP<3>(v, g0); applyGateP<2>(v, g1); applyGateP<1>(v, g2); applyGateP<0>(v, g3);
        #pragma unroll
        for (int j = 0; j < 16; ++j) amp[beta ^ Cm(G(j << 8, K))] = v[j];
        __syncthreads();
    }
    // pass 1: qubits 4-7 (t bits 7-4)
    {
        const GateS g0 = loadGateS(Vs, K * NQ + 4);
        const GateS g1 = loadGateS(Vs, K * NQ + 5);
        const GateS g2 = loadGateS(Vs, K * NQ + 6);
        const GateS g3 = loadGateS(Vs, K * NQ + 7);
        const int beta = Cm(G((Hh << 8) | Lo, K));
        v2f v[16];
        #pragma unroll
        for (int j = 0; j < 16; ++j) v[j] = amp[beta ^ Cm(G(j << 4, K))];
        applyGateP<3>(v, g0); applyGateP<2>(v, g1); applyGateP<1>(v, g2); applyGateP<0>(v, g3);
        #pragma unroll
        for (int j = 0; j < 16; ++j) amp[beta ^ Cm(G(j << 4, K))] = v[j];
        __syncthreads();
    }
    // pass 2: qubits 8-11 (t bits 3-0), b128 along the gamma-fixed direction.
    // read set == write set per thread -> no mid-pass barrier needed.
    {
        const GateS g0 = loadGateS(Vs, K * NQ + 8);
        const GateS g1 = loadGateS(Vs, K * NQ + 9);
        const GateS g2 = loadGateS(Vs, K * NQ + 10);
        const GateS g3 = loadGateS(Vs, K * NQ + 11);
        const int beta = Cm(G((Hh << 8) | (Lo << 4), K));   // bit0 == 0 by construction
        v2f v[16];
        #pragma unroll
        for (int m = 0; m < 8; ++m) {
            const int gg = Cm(G(2 * m, K));                 // compile-time constant
            const float4 F = a4[(beta ^ (gg & ~1)) >> 1];
            const v2f flo = { F.x, F.y }, fhi = { F.z, F.w };
            if (gg & 1) { v[2*m+1] = flo; v[2*m] = fhi; }
            else        { v[2*m] = flo;   v[2*m+1] = fhi; }
        }
        applyGateP<3>(v, g0); applyGateP<2>(v, g1); applyGateP<1>(v, g2); applyGateP<0>(v, g3);
        #pragma unroll
        for (int m = 0; m < 8; ++m) {
            const int gg = Cm(G(2 * m, K));
            float4 F;
            if (gg & 1) F = make_float4(v[2*m+1].x, v[2*m+1].y, v[2*m].x,   v[2*m].y);
            else        F = make_float4(v[2*m].x,   v[2*m].y,   v[2*m+1].x, v[2*m+1].y);
            a4[(beta ^ (gg & ~1)) >> 1] = F;
        }
        __syncthreads();
    }
}

struct c32 { float r, i; };
__device__ __forceinline__ c32 cmul(c32 a, c32 b) {
    return { fmaf(a.r, b.r, -(a.i * b.i)), fmaf(a.r, b.i, a.i * b.r) };
}

__global__ __launch_bounds__(THREADS, 4)
void qcirc_kernel(const float* __restrict__ x, const float* __restrict__ thetas,
                  float* __restrict__ out) {
    __shared__ alignas(16) v2f amp[DIM];      // 32 KB state, layout C.gamma^l
    __shared__ float4 Vs[4 * NQ * 2];         // 48 fused 2x2 gates
    __shared__ float red[4];
    float4* a4 = reinterpret_cast<float4*>(amp);

    const int tid = threadIdx.x;
    const int b = blockIdx.x;

    // ---- fused gate construction: V = RX(t2) RZ(t1) RX(t0) RZ(x2) RY(x1) ----
    const float xv = x[b];
    const float x1 = asinf(xv);
    const float x2 = acosf(xv * xv);
    const float cy = cosf(0.5f * x1), sy = sinf(0.5f * x1);
    const float cz = cosf(0.5f * x2), sz = sinf(0.5f * x2);
    const c32 M00 = {  cz * cy, -sz * cy };
    const c32 M01 = { -cz * sy,  sz * sy };
    const c32 M10 = {  cz * sy,  sz * sy };
    const c32 M11 = {  cz * cy,  sz * cy };

    if (tid < 4 * NQ) {
        const float* th = thetas + tid * 3;
        const float h0 = 0.5f * th[0], h1 = 0.5f * th[1], h2 = 0.5f * th[2];
        const float c0 = cosf(h0), s0 = sinf(h0);
        const float c1 = cosf(h1), s1 = sinf(h1);
        const float c2 = cosf(h2), s2 = sinf(h2);
        const c32 z0 = { c1, -s1 }, z1 = { c1, s1 };
        const c32 X00 = { c0, 0.f }, X01 = { 0.f, -s0 };
        const c32 A00 = cmul(z0, X00), A01 = cmul(z0, X01);
        const c32 A10 = cmul(z1, X01), A11 = cmul(z1, X00);
        const c32 Y00 = { c2, 0.f }, Y01 = { 0.f, -s2 };
        const c32 U00 = { Y00.r*A00.r - Y00.i*A00.i + Y01.r*A10.r - Y01.i*A10.i,
                          Y00.r*A00.i + Y00.i*A00.r + Y01.r*A10.i + Y01.i*A10.r };
        const c32 U01 = { Y00.r*A01.r - Y00.i*A01.i + Y01.r*A11.r - Y01.i*A11.i,
                          Y00.r*A01.i + Y00.i*A01.r + Y01.r*A11.i + Y01.i*A11.r };
        const c32 U10 = { Y01.r*A00.r - Y01.i*A00.i + Y00.r*A10.r - Y00.i*A10.i,
                          Y01.r*A00.i + Y01.i*A00.r + Y00.r*A10.i + Y00.i*A10.r };
        const c32 U11 = { Y01.r*A01.r - Y01.i*A01.i + Y00.r*A11.r - Y00.i*A11.i,
                          Y01.r*A01.i + Y01.i*A01.r + Y00.r*A11.i + Y00.i*A11.r };
        const c32 V00 = { U00.r*M00.r - U00.i*M00.i + U01.r*M10.r - U01.i*M10.i,
                          U00.r*M00.i + U00.i*M00.r + U01.r*M10.i + U01.i*M10.r };
        const c32 V01 = { U00.r*M01.r - U00.i*M01.i + U01.r*M11.r - U01.i*M11.i,
                          U00.r*M01.i + U00.i*M01.r + U01.r*M11.i + U01.i*M11.r };
        const c32 V10 = { U10.r*M00.r - U10.i*M00.i + U11.r*M10.r - U11.i*M10.i,
                          U10.r*M00.i + U10.i*M00.r + U11.r*M10.i + U11.i*M10.r };
        const c32 V11 = { U10.r*M01.r - U10.i*M01.i + U11.r*M11.r - U11.i*M11.i,
                          U10.r*M01.i + U10.i*M01.r + U11.r*M11.i + U11.i*M11.r };
        Vs[tid * 2]     = make_float4(V00.r, V00.i, V01.r, V01.i);
        Vs[tid * 2 + 1] = make_float4(V10.r, V10.i, V11.r, V11.i);
    }
    __syncthreads();

    // ---- layer 0: tensor product computed directly, written at layout C ----
    {
        v2f C = { 1.f, 0.f };
        #pragma unroll
        for (int q = 0; q < 8; ++q) {
            const float4 r0 = Vs[q * 2];
            const float4 r1 = Vs[q * 2 + 1];
            const bool bit = (tid >> (7 - q)) & 1;
            const v2f e = { bit ? r1.x : r0.x, bit ? r1.y : r0.y };
            C = cmulp(C, e);
        }
        v2f e8[2], e9[2], e10[2], e11[2];
        {
            float4 a, c;
            a = Vs[8*2];  c = Vs[8*2+1];  e8[0]  = { a.x, a.y }; e8[1]  = { c.x, c.y };
            a = Vs[9*2];  c = Vs[9*2+1];  e9[0]  = { a.x, a.y }; e9[1]  = { c.x, c.y };
            a = Vs[10*2]; c = Vs[10*2+1]; e10[0] = { a.x, a.y }; e10[1] = { c.x, c.y };
            a = Vs[11*2]; c = Vs[11*2+1]; e11[0] = { a.x, a.y }; e11[1] = { c.x, c.y };
        }
        v2f CP[4], Q[4];
        #pragma unroll
        for (int aa = 0; aa < 2; ++aa)
            #pragma unroll
            for (int d = 0; d < 2; ++d) {
                CP[aa * 2 + d] = cmulp(cmulp(C, e8[aa]), e9[d]);
                Q[aa * 2 + d]  = cmulp(e10[aa], e11[d]);
            }
        v2f w[16];
        #pragma unroll
        for (int j = 0; j < 16; ++j) w[j] = cmulp(CP[j >> 2], Q[j & 3]);
        const int beta = Cm(tid << 4);        // even; Cm(j)=j for j<16
        #pragma unroll
        for (int m = 0; m < 8; ++m)
            a4[(beta ^ (2 * m)) >> 1] =
                make_float4(w[2*m].x, w[2*m].y, w[2*m+1].x, w[2*m+1].y);
    }
    __syncthreads();

    // ---- layers 1..3 (CNOT ladders folded into addressing) ----
    doLayer<1>(amp, a4, Vs, tid);
    doLayer<2>(amp, a4, Vs, tid);
    doLayer<3>(amp, a4, Vs, tid);

    // ---- readout: weight = parity(MASKE & e); final CNOT folded into MASKE ----
    float acc = 0.f;
    #pragma unroll
    for (int it = 0; it < 8; ++it) {
        const int pe = (it << 9) | (tid << 1);
        const float4 F = a4[pe >> 1];
        const float m0 = fmaf(F.x, F.x, F.y * F.y);
        const float m1 = fmaf(F.z, F.z, F.w * F.w);
        acc += (__popc(pe & MASKE) & 1) ? -m0 : m0;
        acc += (__popc((pe | 1) & MASKE) & 1) ? -m1 : m1;
    }
    #pragma unroll
    for (int off = 32; off > 0; off >>= 1) acc += __shfl_down(acc, off, 64);
    if ((tid & 63) == 0) red[tid >> 6] = acc;
    __syncthreads();
    if (tid == 0) out[b] = red[0] + red[1] + red[2] + red[3];
}

} // namespace

extern "C" void kernel_launch(void* const* d_in, const int* in_sizes, int n_in,
                              void* d_out, int out_size, void* d_ws, size_t ws_size,
                              hipStream_t stream) {
    const float* x      = (const float*)d_in[0];
    const float* thetas = (const float*)d_in[1];
    float* out          = (float*)d_out;
    const int batch = in_sizes[0];
    qcirc_kernel<<<batch, THREADS, 0, stream>>>(x, thetas, out);
}